// Round 10
// baseline (206.604 us; speedup 1.0000x reference)
//
#include <hip/hip_runtime.h>

typedef unsigned short u16;
typedef __bf16 bf16x8 __attribute__((ext_vector_type(8)));
typedef float f32x4 __attribute__((ext_vector_type(4)));
typedef unsigned u32x4 __attribute__((ext_vector_type(4)));

__device__ __forceinline__ float b2f(u16 x) {
    union { float f; unsigned u; } v; v.u = ((unsigned)x) << 16; return v.f;
}
__device__ __forceinline__ u16 f2b(float f) {
    union { float f; unsigned u; } v; v.f = f;
    unsigned u = v.u;
    return (u16)((u + 0x7FFFu + ((u >> 16) & 1u)) >> 16);
}
// pack two f32 -> two truncated bf16 in one dword (lo=a, hi=b)
__device__ __forceinline__ unsigned pk2(float a, float b) {
    unsigned ua = __float_as_uint(a), ub = __float_as_uint(b);
    return (ub & 0xFFFF0000u) | (ua >> 16);
}
__device__ __forceinline__ f32x4 mfma_16x16x32(bf16x8 a, bf16x8 b, f32x4 c) {
    return __builtin_amdgcn_mfma_f32_16x16x32_bf16(a, b, c, 0, 0, 0);
}
// async global->LDS, 16B per lane. LDS dest = wave-uniform base + lane*16.
__device__ __forceinline__ void gld_lds16(const u16* g, u16* l) {
    __builtin_amdgcn_global_load_lds(
        (const __attribute__((address_space(1))) unsigned int*)g,
        (__attribute__((address_space(3))) unsigned int*)l,
        16, 0, 0);
}

#define VSTRIDE 2080
#define LOG2E 1.44269504f

// ---------------------------------------------------------------------------
// prep: inputs f32->bf16 [0,4096); W_in T+cvt [4096,7168); W_out T+cvt [7168,8192)
// ---------------------------------------------------------------------------
__global__ __launch_bounds__(256) void prep(const float* __restrict__ inputs,
                                            u16* __restrict__ inB,
                                            const float* __restrict__ W_in,
                                            u16* __restrict__ WtB,
                                            const float* __restrict__ W_out,
                                            u16* __restrict__ WotB) {
    __shared__ float T[32][33];
    const int bx = blockIdx.x;
    if (bx < 4096) {
        int i = (bx * 256 + threadIdx.x) * 4;
        float4 v = *(const float4*)(inputs + i);
        ushort4 o;
        o.x = f2b(v.x); o.y = f2b(v.y); o.z = f2b(v.z); o.w = f2b(v.w);
        *(ushort4*)(inB + i) = o;
        return;
    }
    const float* src; u16* dst; int R, C, c0, r0;
    if (bx < 7168) {
        int t = bx - 4096; src = W_in; dst = WtB; R = 1024; C = 3072;
        c0 = (t % 96) * 32; r0 = (t / 96) * 32;
    } else {
        int t = bx - 7168; src = W_out; dst = WotB; R = 1024; C = 1024;
        c0 = (t % 32) * 32; r0 = (t / 32) * 32;
    }
    int tr = threadIdx.x >> 5, tc = threadIdx.x & 31;
#pragma unroll
    for (int p = 0; p < 4; ++p)
        T[tr + p * 8][tc] = src[(size_t)(r0 + tr + p * 8) * C + c0 + tc];
    __syncthreads();
#pragma unroll
    for (int p = 0; p < 4; ++p)
        dst[(size_t)(c0 + tr + p * 8) * R + r0 + tc] = f2b(T[tc][tr + p * 8]);
}

// ---------------------------------------------------------------------------
// GEMM (gemm1): C[M,N] = A[M,K] * Bt[N,K]^T. bf16 in, 2-phase pipelined
// staging (double-buffered LDS, counted vmcnt, raw s_barrier). BM=128.
// ---------------------------------------------------------------------------
template <int BM, bool F32OUT>
__global__ __launch_bounds__(256) void gemm_tn(const u16* __restrict__ A,
                                               const u16* __restrict__ Bt,
                                               void* __restrict__ Cv,
                                               int M, int N, int K) {
    __shared__ u16 As[2][BM * 32];
    __shared__ u16 Bs[2][128 * 32];
    const int tid = threadIdx.x;
    const int m0 = blockIdx.y * BM;
    const int n0 = blockIdx.x * 128;
    const int w = tid >> 6, lane = tid & 63;
    const int col16 = lane & 15, quad = lane >> 4;
    constexpr int MI = BM / 32;                  // 4 for BM=128
    const int wm = (w >> 1) * (BM / 2), wn = (w & 1) * 64;
    const int srow = (lane >> 2), sseg = (lane & 3) * 8;

    f32x4 acc[MI][4];
#pragma unroll
    for (int i = 0; i < MI; ++i)
#pragma unroll
        for (int j = 0; j < 4; ++j) acc[i][j] = (f32x4){0.f, 0.f, 0.f, 0.f};

    // ---- prologue: stage k-step 0 into buf 0 ----
    if (BM == 128) {
#pragma unroll
        for (int cc = 0; cc < 2; ++cc) {
            int c = w * 2 + cc, row = c * 16 + srow;
            gld_lds16(A + (size_t)(m0 + row) * K + sseg, &As[0][c * 512 + lane * 8]);
            gld_lds16(Bt + (size_t)(n0 + row) * K + sseg, &Bs[0][c * 512 + lane * 8]);
        }
    } else {
        int row = w * 16 + srow;
        gld_lds16(A + (size_t)(m0 + row) * K + sseg, &As[0][w * 512 + lane * 8]);
#pragma unroll
        for (int cc = 0; cc < 2; ++cc) {
            int c = w * 2 + cc, rowb = c * 16 + srow;
            gld_lds16(Bt + (size_t)(n0 + rowb) * K + sseg, &Bs[0][c * 512 + lane * 8]);
        }
    }

    const int NK = K >> 5;
    for (int ki = 0; ki < NK; ++ki) {
        const int cur = ki & 1;
        if (ki + 1 < NK) {
            const int kt = (ki + 1) << 5;
            // ---- stage next k-step into the other buffer ----
            if (BM == 128) {
#pragma unroll
                for (int cc = 0; cc < 2; ++cc) {
                    int c = w * 2 + cc, row = c * 16 + srow;
                    gld_lds16(A + (size_t)(m0 + row) * K + kt + sseg, &As[cur ^ 1][c * 512 + lane * 8]);
                    gld_lds16(Bt + (size_t)(n0 + row) * K + kt + sseg, &Bs[cur ^ 1][c * 512 + lane * 8]);
                }
                asm volatile("s_waitcnt vmcnt(4)" ::: "memory");
            } else {
                int row = w * 16 + srow;
                gld_lds16(A + (size_t)(m0 + row) * K + kt + sseg, &As[cur ^ 1][w * 512 + lane * 8]);
#pragma unroll
                for (int cc = 0; cc < 2; ++cc) {
                    int c = w * 2 + cc, rowb = c * 16 + srow;
                    gld_lds16(Bt + (size_t)(n0 + rowb) * K + kt + sseg, &Bs[cur ^ 1][c * 512 + lane * 8]);
                }
                asm volatile("s_waitcnt vmcnt(3)" ::: "memory");
            }
        } else {
            asm volatile("s_waitcnt vmcnt(0)" ::: "memory");
        }
        asm volatile("s_barrier" ::: "memory");

        bf16x8 af[MI], bfr[4];
#pragma unroll
        for (int i = 0; i < MI; ++i)
            af[i] = *(const bf16x8*)&As[cur][(wm + i * 16 + col16) * 32 + quad * 8];
#pragma unroll
        for (int j = 0; j < 4; ++j)
            bfr[j] = *(const bf16x8*)&Bs[cur][(wn + j * 16 + col16) * 32 + quad * 8];
#pragma unroll
        for (int i = 0; i < MI; ++i)
#pragma unroll
            for (int j = 0; j < 4; ++j)
                acc[i][j] = mfma_16x16x32(af[i], bfr[j], acc[i][j]);

        // LDS reads of buf[cur] done before next iteration overwrites it
        asm volatile("s_waitcnt lgkmcnt(0)" ::: "memory");
        asm volatile("s_barrier" ::: "memory");
    }

#pragma unroll
    for (int i = 0; i < MI; ++i) {
#pragma unroll
        for (int r = 0; r < 4; ++r) {
            int m = m0 + wm + i * 16 + quad * 4 + r;
            if (F32OUT) {
                float* Crow = (float*)Cv + (size_t)m * N + n0 + wn;
#pragma unroll
                for (int j = 0; j < 4; ++j)
                    Crow[j * 16 + col16] = acc[i][j][r];
            } else {
                u16* Crow = (u16*)Cv + (size_t)m * N + n0 + wn;
#pragma unroll
                for (int j = 0; j < 4; ++j)
                    Crow[j * 16 + col16] = f2b(acc[i][j][r]);
            }
        }
    }
}

// ---------------------------------------------------------------------------
// gemm2: C[M,N](f32) = A[M,K] * Bt[N,K]^T, BM=64 x BN=64 x BK=64.
// Grid (N/64, M/64) = 1024 = 4 blocks/CU. XOR-swizzled LDS (both sides).
// ---------------------------------------------------------------------------
__global__ __launch_bounds__(256) void gemm_tn64(const u16* __restrict__ A,
                                                 const u16* __restrict__ Bt,
                                                 float* __restrict__ C,
                                                 int M, int N, int K) {
    __shared__ u16 As[2][64 * 64];   // [buf][row][64 k]  (8KB/buf)
    __shared__ u16 Bs[2][64 * 64];
    const int tid = threadIdx.x;
    const int m0 = blockIdx.y * 64;
    const int n0 = blockIdx.x * 64;
    const int w = tid >> 6, lane = tid & 63;
    const int col16 = lane & 15, quad = lane >> 4;
    const int wm = (w >> 1) * 32, wn = (w & 1) * 32;
    // staging decomposition: each gld_lds covers 8 rows x 128B; lane = r*8+s.
    const int sr = lane >> 3;              // row within instr (0..7)
    const int sg = ((lane & 7) ^ sr) * 8;  // pre-swizzled 16B granule (u16 units)
    const int swz = (col16 & 7) << 3;      // row-XOR on fragment reads

    f32x4 acc[2][2];
#pragma unroll
    for (int i = 0; i < 2; ++i)
#pragma unroll
        for (int j = 0; j < 2; ++j) acc[i][j] = (f32x4){0.f, 0.f, 0.f, 0.f};

    // ---- prologue: stage k-step 0 into buf 0 (4 instrs/wave: 2 A + 2 B) ----
#pragma unroll
    for (int i = 0; i < 2; ++i) {
        int c = w * 2 + i;
        gld_lds16(A + (size_t)(m0 + c * 8 + sr) * K + sg, &As[0][c * 512 + lane * 8]);
    }
#pragma unroll
    for (int i = 0; i < 2; ++i) {
        int c = w * 2 + i;
        gld_lds16(Bt + (size_t)(n0 + c * 8 + sr) * K + sg, &Bs[0][c * 512 + lane * 8]);
    }

    const int NK = K >> 6;                 // 16 steps
    for (int ki = 0; ki < NK; ++ki) {
        const int cur = ki & 1;
        if (ki + 1 < NK) {
            const int kt = (ki + 1) << 6;
#pragma unroll
            for (int i = 0; i < 2; ++i) {
                int c = w * 2 + i;
                gld_lds16(A + (size_t)(m0 + c * 8 + sr) * K + kt + sg, &As[cur ^ 1][c * 512 + lane * 8]);
            }
#pragma unroll
            for (int i = 0; i < 2; ++i) {
                int c = w * 2 + i;
                gld_lds16(Bt + (size_t)(n0 + c * 8 + sr) * K + kt + sg, &Bs[cur ^ 1][c * 512 + lane * 8]);
            }
            // wait only for CURRENT step's 4 loads; next step's 4 stay in flight
            asm volatile("s_waitcnt vmcnt(4)" ::: "memory");
        } else {
            asm volatile("s_waitcnt vmcnt(0)" ::: "memory");
        }
        asm volatile("s_barrier" ::: "memory");

#pragma unroll
        for (int ks = 0; ks < 2; ++ks) {
            const int ko = (ks * 32 + quad * 8) ^ swz;
            bf16x8 af[2], bfr[2];
#pragma unroll
            for (int i = 0; i < 2; ++i)
                af[i] = *(const bf16x8*)&As[cur][(wm + i * 16 + col16) * 64 + ko];
#pragma unroll
            for (int j = 0; j < 2; ++j)
                bfr[j] = *(const bf16x8*)&Bs[cur][(wn + j * 16 + col16) * 64 + ko];
#pragma unroll
            for (int i = 0; i < 2; ++i)
#pragma unroll
                for (int j = 0; j < 2; ++j)
                    acc[i][j] = mfma_16x16x32(af[i], bfr[j], acc[i][j]);
        }

        // LDS reads of buf[cur] done before next iteration overwrites it
        asm volatile("s_waitcnt lgkmcnt(0)" ::: "memory");
        asm volatile("s_barrier" ::: "memory");
    }

#pragma unroll
    for (int i = 0; i < 2; ++i) {
#pragma unroll
        for (int r = 0; r < 4; ++r) {
            int m = m0 + wm + i * 16 + quad * 4 + r;
            float* Crow = C + (size_t)m * N + n0 + wn;
#pragma unroll
            for (int j = 0; j < 2; ++j)
                Crow[j * 16 + col16] = acc[i][j][r];
        }
    }
}

// ---------------------------------------------------------------------------
// Fused rope + v_transpose. blocks [0,1024): RoPE (q scaled log2e/8);
// blocks [1024,3072): V transpose into Vt [BH][64][VSTRIDE].
// ---------------------------------------------------------------------------
__global__ __launch_bounds__(256) void rope_vt(const u16* __restrict__ qkv,
                                               const int* __restrict__ segpos,
                                               u16* __restrict__ Qh,
                                               u16* __restrict__ Kh,
                                               u16* __restrict__ Vt) {
    __shared__ u16 T[32][72];
    const int bx = blockIdx.x;
    if (bx < 1024) {
        int t = bx * 256 + threadIdx.x;
        int seg = t & 3;
        int h = (t >> 2) & 15;
        int row = t >> 6;
        float pos = (float)segpos[row];
        const u16* base = qkv + (size_t)row * 3072 + h * 192 + seg * 8;
        union { uint4 u; u16 s[8]; } q1, q2, k1, k2, oq1, oq2, ok1, ok2;
        q1.u = *(const uint4*)(base);
        q2.u = *(const uint4*)(base + 32);
        k1.u = *(const uint4*)(base + 64);
        k2.u = *(const uint4*)(base + 96);
        const float qs = 0.125f * LOG2E;
#pragma unroll
        for (int j = 0; j < 8; ++j) {
            int d = seg * 8 + j;
            float inv_freq = __expf(-(float)d * (9.210340371976184f / 32.0f));
            float ang = pos * inv_freq;
            float c = __cosf(ang), s = __sinf(ang);
            float a1 = b2f(q1.s[j]), a2 = b2f(q2.s[j]);
            float b1 = b2f(k1.s[j]), b2v = b2f(k2.s[j]);
            oq1.s[j] = f2b((a1 * c - a2 * s) * qs);
            oq2.s[j] = f2b((a1 * s + a2 * c) * qs);
            ok1.s[j] = f2b(b1 * c - b2v * s);
            ok2.s[j] = f2b(b1 * s + b2v * c);
        }
        int b = row >> 11, srow = row & 2047;
        size_t idx = ((size_t)(b * 16 + h) * 2048 + srow) * 64 + seg * 8;
        *(uint4*)&Qh[idx]      = oq1.u;
        *(uint4*)&Qh[idx + 32] = oq2.u;
        *(uint4*)&Kh[idx]      = ok1.u;
        *(uint4*)&Kh[idx + 32] = ok2.u;
        return;
    }
    int bxx = bx - 1024;
    int s0 = (bxx & 63) * 32;
    int bh = bxx >> 6;
    int b = bh >> 4, h = bh & 15;
    int t = threadIdx.x;
    {
        int r = t >> 3, seg = t & 7;
        const u16* src = qkv + (size_t)(b * 2048 + s0 + r) * 3072 + h * 192 + 128 + seg * 8;
        *(uint4*)&T[r][seg * 8] = *(const uint4*)src;
    }
    __syncthreads();
    {
        int d = t >> 2, ss = (t & 3) * 8;
        union { uint4 u; u16 s[8]; } w;
#pragma unroll
        for (int j = 0; j < 8; ++j) w.s[j] = T[ss + j][d];
        *(uint4*)(Vt + (size_t)bh * 64 * VSTRIDE + (size_t)d * VSTRIDE + s0 + ss) = w.u;
    }
}

// ---------------------------------------------------------------------------
// Flash attention v17 = v9 with the P-LDS round-trip replaced by an
// in-register shuffle exchange (T12-style):
//  - lane (col16,quad) holds P[q=col16][k=kt*16+quad*4+r]; the PV A-fragment
//    needs P[col16][ss*32+quad*8+j]. Target dword j-pair == source lane's
//    pk2(p[r],p[r+1]) pack with kt=2ss+(quad>>1), src lane = col16 +
//    (quad&1)*32 (+16). Both kt parities shuffled, selected by quad>>1
//    (shfl operand is evaluated on the SOURCE lane -> cannot fold the
//    select into the shfl).
//  - Ps deleted: LDS 49.7 -> 33.3KB => 4 blocks/CU, grid 864 all-resident.
//  - softmax->PV lgkm drains removed (no LDS dependency).
// Everything else (split tables, staging, QK^T, epilogue) v9-verbatim.
// ---------------------------------------------------------------------------
#define FIXED_M2 34.6246561f    // 24 * log2(e)

// per-bh unit tables, execution-ordered by descending chunk count (LPT).
__device__ const int UTQ[27] = {6,7,8,9,10,11,12,13,13,14,14,15,15, 5,12, 4,11, 3,10, 2,9, 1,8,15, 0,7,14};
__device__ const int UK0[27] = {0,0,0,0,0,0,0,0,14,0,14,0,14, 0,14, 0,14, 0,14, 0,14, 0,14,28, 0,14,28};
__device__ const int UNC[27] = {14,14,14,14,14,14,14,14,14,14,14,14,14, 12,12, 10,10, 8,8, 6,6, 4,4,4, 2,2,2};
__device__ const int UPS[27] = {-1,0,1,2,3,4,5,6,7,8,9,10,11, -1,12, -1,13, -1,14, -1,15, -1,16,17, -1,18,19};
// reduce tables: tiles tq = 7 + ti, ti in [0,9)
__device__ const int RUN[9]    = {2,2,2,2,2,2,2,3,3};
__device__ const int RUS[9][3] = {{0,18,-1},{1,16,-1},{2,15,-1},{3,14,-1},{4,13,-1},
                                  {5,12,-1},{6,7,-1},{8,9,19},{10,11,17}};

__global__ __launch_bounds__(256) void attn_v17(const u16* __restrict__ Qh,
                                                const u16* __restrict__ Kh,
                                                const u16* __restrict__ Vt,
                                                u16* __restrict__ X,
                                                float* __restrict__ Opart,
                                                float* __restrict__ Lpart) {
    __shared__ u16 Ks[2][64 * 64];   // [buf][k-row][64 d]  (8KB/buf)
    __shared__ u16 Vs[2][64 * 64];   // [buf][d-row][64 k]  (8KB/buf)
    __shared__ float lred[4][32];
    const int tid = threadIdx.x;
    const int w = tid >> 6, lane = tid & 63;
    const int col16 = lane & 15, quad = lane >> 4;
    // XCD-aware block swizzle: 864 = 8 XCD x 108; each XCD owns 4 bh.
    const int raw = blockIdx.x;
    const int bsw = (raw & 7) * 108 + (raw >> 3);
    const int bh = bsw / 27;
    const int slot = bsw - bh * 27;
    const int tq = UTQ[slot];
    const int c0 = UK0[slot];
    const int nc = UNC[slot];
    const int ps = UPS[slot];
    const int q0 = tq * 128 + w * 32;
    const u16* Qp = Qh + (size_t)bh * 2048 * 64;
    const u16* Kp = Kh + (size_t)bh * 2048 * 64;
    const u16* Vp = Vt + (size_t)bh * 64 * VSTRIDE;
    const int swz = (col16 & 7) << 3;      // row-XOR for K/V LDS tiles (u16 units)
    // shuffle-exchange source lanes (see header comment)
    const int srcA = col16 + ((lane & 16) << 1);   // col16 + (quad&1)*32
    const int srcB = srcA + 16;
    const bool hisel = (quad >> 1) != 0;

    // Q fragments (used as B-operand of K*Q^T -- identical lane data)
    bf16x8 qa[2][2];
#pragma unroll
    for (int t = 0; t < 2; ++t)
#pragma unroll
        for (int hf = 0; hf < 2; ++hf)
            qa[t][hf] = *(const bf16x8*)&Qp[(size_t)(q0 + t * 16 + col16) * 64 + hf * 32 + quad * 8];

    float l_acc[2] = {0.f, 0.f};
    f32x4 o[2][4];
#pragma unroll
    for (int t = 0; t < 2; ++t)
#pragma unroll
        for (int f = 0; f < 4; ++f) o[t][f] = (f32x4){0.f, 0.f, 0.f, 0.f};

    // staging decomposition: each gld_lds covers 8 rows x 128B; lane = r*8+s.
    // swizzled granule: global slot = s ^ r  (involution; read applies same XOR)
    const int sr = lane >> 3;              // row within instr (0..7)
    const int sg = ((lane & 7) ^ sr) * 8;  // pre-swizzled 16B granule (u16 units)

    // ---- prologue: stage chunk c0 into buf 0 (4 instrs/wave: 2 K + 2 V) ----
    {
        const int k0 = c0 * 64;
#pragma unroll
        for (int i = 0; i < 2; ++i) {
            int c = w * 2 + i;
            gld_lds16(Kp + (size_t)(k0 + c * 8 + sr) * 64 + sg, &Ks[0][c * 512 + lane * 8]);
        }
#pragma unroll
        for (int i = 0; i < 2; ++i) {
            int c = w * 2 + i;
            gld_lds16(Vp + (size_t)(c * 8 + sr) * VSTRIDE + k0 + sg, &Vs[0][c * 512 + lane * 8]);
        }
    }

    for (int ci = 0; ci < nc; ++ci) {
        const int cur = ci & 1;
        const u16* KsC = Ks[cur];
        const u16* VsC = Vs[cur];

        // ---- issue next chunk's stage into the other buffer ----
        if (ci + 1 < nc) {
            const int k0n = (c0 + ci + 1) * 64;
            u16* Kd = Ks[cur ^ 1];
            u16* Vd = Vs[cur ^ 1];
#pragma unroll
            for (int i = 0; i < 2; ++i) {
                int c = w * 2 + i;
                gld_lds16(Kp + (size_t)(k0n + c * 8 + sr) * 64 + sg, Kd + c * 512 + lane * 8);
            }
#pragma unroll
            for (int i = 0; i < 2; ++i) {
                int c = w * 2 + i;
                gld_lds16(Vp + (size_t)(c * 8 + sr) * VSTRIDE + k0n + sg, Vd + c * 512 + lane * 8);
            }
            // wait only for CURRENT chunk's 4 loads; next chunk's 4 stay in flight
            asm volatile("s_waitcnt vmcnt(4)" ::: "memory");
        } else {
            asm volatile("s_waitcnt vmcnt(0)" ::: "memory");
        }
        asm volatile("s_barrier" ::: "memory");

        const int k0 = (c0 + ci) * 64;

        // ---- K*Q^T -> S^T ----
        f32x4 s[2][4];
#pragma unroll
        for (int t = 0; t < 2; ++t)
#pragma unroll
            for (int kt = 0; kt < 4; ++kt) s[t][kt] = (f32x4){0.f, 0.f, 0.f, 0.f};
#pragma unroll
        for (int kt = 0; kt < 4; ++kt) {
            const u16* kb = &KsC[(kt * 16 + col16) * 64];
            bf16x8 kf0 = *(const bf16x8*)&kb[(quad * 8) ^ swz];
            bf16x8 kf1 = *(const bf16x8*)&kb[(32 + quad * 8) ^ swz];
            s[0][kt] = mfma_16x16x32(kf0, qa[0][0], s[0][kt]);
            s[0][kt] = mfma_16x16x32(kf1, qa[0][1], s[0][kt]);
            s[1][kt] = mfma_16x16x32(kf0, qa[1][0], s[1][kt]);
            s[1][kt] = mfma_16x16x32(kf1, qa[1][1], s[1][kt]);
        }

        // ---- softmax: p = 2^(s - M2), per-lane l, packed dword pairs ----
        const bool domask = (k0 + 63 > q0);
        unsigned pkv[2][4][2];   // [t][kt][dword] -- all indices compile-time
#pragma unroll
        for (int t = 0; t < 2; ++t) {
            const int qg = q0 + t * 16 + col16;
            float rs = 0.f;
#pragma unroll
            for (int kt = 0; kt < 4; ++kt) {
                float p[4];
#pragma unroll
                for (int r = 0; r < 4; ++r) {
                    float sv = s[t][kt][r];
                    if (domask && (k0 + kt * 16 + quad * 4 + r > qg)) sv = -1e30f;
                    p[r] = __builtin_amdgcn_exp2f(sv - FIXED_M2);
                    rs += p[r];
                }
                pkv[t][kt][0] = pk2(p[0], p[1]);
                pkv[t][kt][1] = pk2(p[2], p[3]);
            }
            l_acc[t] += rs;
        }

        // ---- register exchange: build PV A-fragments (no LDS) ----
        u32x4 pf[2][2];          // [t][ss] as 4 dwords = bf16x8
#pragma unroll
        for (int t = 0; t < 2; ++t) {
#pragma unroll
            for (int ssi = 0; ssi < 2; ++ssi) {
                // even kt (=2ss) feeds quads 0,1; odd kt (=2ss+1) feeds quads 2,3
                unsigned e0 = (unsigned)__shfl((int)pkv[t][2 * ssi][0], srcA);
                unsigned e1 = (unsigned)__shfl((int)pkv[t][2 * ssi][1], srcA);
                unsigned e2 = (unsigned)__shfl((int)pkv[t][2 * ssi][0], srcB);
                unsigned e3 = (unsigned)__shfl((int)pkv[t][2 * ssi][1], srcB);
                unsigned o0 = (unsigned)__shfl((int)pkv[t][2 * ssi + 1][0], srcA);
                unsigned o1 = (unsigned)__shfl((int)pkv[t][2 * ssi + 1][1], srcA);
                unsigned o2 = (unsigned)__shfl((int)pkv[t][2 * ssi + 1][0], srcB);
                unsigned o3 = (unsigned)__shfl((int)pkv[t][2 * ssi + 1][1], srcB);
                u32x4 d;
                d[0] = hisel ? o0 : e0;
                d[1] = hisel ? o1 : e1;
                d[2] = hisel ? o2 : e2;
                d[3] = hisel ? o3 : e3;
                pf[t][ssi] = d;
            }
        }

        // ---- PV: 16 MFMAs (A-operand from registers) ----
#pragma unroll
        for (int ssi = 0; ssi < 2; ++ssi) {
            const int ko = (ssi * 32 + quad * 8) ^ swz;
            bf16x8 pf0, pf1;
            __builtin_memcpy(&pf0, &pf[0][ssi], 16);
            __builtin_memcpy(&pf1, &pf[1][ssi], 16);
#pragma unroll
            for (int f = 0; f < 4; ++f) {
                bf16x8 vf = *(const bf16x8*)&VsC[(f * 16 + col16) * 64 + ko];
                o[0][f] = mfma_16x16x32(pf0, vf, o[0][f]);
                o[1][f] = mfma_16x16x32(pf1, vf, o[1][f]);
            }
        }
        // all LDS reads of buf[cur] complete before next staging overwrites
        asm volatile("s_waitcnt lgkmcnt(0)" ::: "memory");
        asm volatile("s_barrier" ::: "memory");
    }

    // ---- l reduction across quads (butterfly -> every lane has row total) ----
    float lt[2];
#pragma unroll
    for (int t = 0; t < 2; ++t) {
        float l = l_acc[t];
        l += __shfl_xor(l, 16);
        l += __shfl_xor(l, 32);
        lt[t] = l;
        if (quad == 0) lred[w][t * 16 + col16] = l;
    }
    asm volatile("s_waitcnt lgkmcnt(0)" ::: "memory");

    if (ps >= 0) {
        // ---- partial epilogue: raw O (no divide) + l to workspace ----
        const int pg = bh * 20 + ps;
        float* Op = Opart + ((size_t)pg * 128 + w * 32) * 64;
#pragma unroll
        for (int t = 0; t < 2; ++t) {
#pragma unroll
            for (int r = 0; r < 4; ++r) {
                float* Crow = Op + (t * 16 + quad * 4 + r) * 64;
#pragma unroll
                for (int f = 0; f < 4; ++f)
                    Crow[f * 16 + col16] = o[t][f][r];
            }
        }
        if (quad == 0) {
            float* Lp = Lpart + (size_t)pg * 128 + w * 32;
#pragma unroll
            for (int t = 0; t < 2; ++t) Lp[t * 16 + col16] = lt[t];
        }
        return;
    }

    // ---- direct epilogue (single-unit tile): divide and write X ----
    const int b = bh >> 4, h = bh & 15;
#pragma unroll
    for (int t = 0; t < 2; ++t) {
#pragma unroll
        for (int r = 0; r < 4; ++r) {
            float inv = 1.0f / lred[w][t * 16 + quad * 4 + r];
            int srow = q0 + t * 16 + quad * 4 + r;
            u16* Xp = X + ((size_t)(b * 2048 + srow)) * 1024 + h * 64;
#pragma unroll
            for (int f = 0; f < 4; ++f)
                Xp[f * 16 + col16] = f2b(o[t][f][r] * inv);
        }
    }
}

// ---------------------------------------------------------------------------
// attn_reduce: combine 2-3 partials per (bh, tq in 7..15): X = (sum O)/(sum l)
// ---------------------------------------------------------------------------
__global__ __launch_bounds__(256) void attn_reduce(const float* __restrict__ Opart,
                                                   const float* __restrict__ Lpart,
                                                   u16* __restrict__ X) {
    const int bh = blockIdx.x;           // 0..31
    const int ti = blockIdx.y;           // 0..8 -> tq = 7+ti
    const int tq = 7 + ti;
    const int tid = threadIdx.x;
    const int b = bh >> 4, h = bh & 15;
    const int np = RUN[ti];
    const size_t g0 = (size_t)(bh * 20 + RUS[ti][0]);
    const size_t g1 = (size_t)(bh * 20 + RUS[ti][1]);
    const size_t g2 = (np > 2) ? (size_t)(bh * 20 + RUS[ti][2]) : 0;
    const float4* O0 = (const float4*)Opart + g0 * 2048;
    const float4* O1 = (const float4*)Opart + g1 * 2048;
    const float4* O2 = (const float4*)Opart + g2 * 2048;
#pragma unroll
    for (int i = 0; i < 8; ++i) {
        int e4 = i * 256 + tid;          // float4 index within 128x64 tile
        int q = e4 >> 4, d0 = (e4 & 15) * 4;
        float4 a = O0[e4];
        float4 c = O1[e4];
        a.x += c.x; a.y += c.y; a.z += c.z; a.w += c.w;
        float l = Lpart[g0 * 128 + q] + Lpart[g1 * 128 + q];
        if (np > 2) {
            float4 d = O2[e4];
            a.x += d.x; a.y += d.y; a.z += d.z; a.w += d.w;
            l += Lpart[g2 * 128 + q];
        }
        float inv = 1.0f / l;
        ushort4 ov;
        ov.x = f2b(a.x * inv); ov.y = f2b(a.y * inv);
        ov.z = f2b(a.z * inv); ov.w = f2b(a.w * inv);
        *(ushort4*)&X[((size_t)(b * 2048 + tq * 128 + q)) * 1024 + h * 64 + d0] = ov;
    }
}

// ---------------------------------------------------------------------------
// launch
// ---------------------------------------------------------------------------
extern "C" void kernel_launch(void* const* d_in, const int* in_sizes, int n_in,
                              void* d_out, int out_size, void* d_ws, size_t ws_size,
                              hipStream_t stream) {
    const float* inputs = (const float*)d_in[0];
    const int* segpos   = (const int*)d_in[1];
    const float* W_in   = (const float*)d_in[3];
    const float* W_out  = (const float*)d_in[4];
    float* out = (float*)d_out;

    u16* ws = (u16*)d_ws;
    u16* qkv   = ws;                               // 4096*3072 bf16
    u16* x     = qkv;                              // alias (qkv dead after rope_vt)
    u16* inB   = qkv + 12582912 + 512;
    u16* WtB   = inB + 4194304 + 512;              // W_in^T  [3072][1024]
    u16* WotB  = WtB + 3145728 + 512;              // W_out^T [1024][1024]
    u16* Qh    = WotB + 1048576 + 512;             // [BH][S][64]
    u16* Kh    = Qh + 4194304 + 512;
    u16* Vt    = Kh + 4194304 + 512;               // [BH][64][VSTRIDE]
    // split-K partials live in qkv[8.39M..]/inB/WtB space (dead during attn):
    // Opart: 640 slots x 128 x 64 f32 = 10,485,760 u16; Lpart: 640 x 128 f32.
    float* Opart = (float*)(ws + 8388608);
    float* Lpart = (float*)(ws + 8388608 + 10485760);

    prep<<<dim3(8192), 256, 0, stream>>>(inputs, inB, W_in, WtB, W_out, WotB);
    gemm_tn<128, false><<<dim3(24, 32), 256, 0, stream>>>(inB, WtB, qkv, 4096, 3072, 1024);
    rope_vt<<<dim3(3072), 256, 0, stream>>>(qkv, segpos, Qh, Kh, Vt);
    attn_v17<<<dim3(864), 256, 0, stream>>>(Qh, Kh, Vt, x, Opart, Lpart);
    attn_reduce<<<dim3(32, 9), 256, 0, stream>>>(Opart, Lpart, x);
    gemm_tn64<<<dim3(16, 64), 256, 0, stream>>>(x, WotB, out, 4096, 1024, 1024);
}

// Round 11
// 201.454 us; speedup vs baseline: 1.0256x; 1.0256x over previous
//
#include <hip/hip_runtime.h>

typedef unsigned short u16;
typedef __bf16 bf16x8 __attribute__((ext_vector_type(8)));
typedef float f32x4 __attribute__((ext_vector_type(4)));

__device__ __forceinline__ float b2f(u16 x) {
    union { float f; unsigned u; } v; v.u = ((unsigned)x) << 16; return v.f;
}
__device__ __forceinline__ u16 f2b(float f) {
    union { float f; unsigned u; } v; v.f = f;
    unsigned u = v.u;
    return (u16)((u + 0x7FFFu + ((u >> 16) & 1u)) >> 16);
}
// pack two f32 -> two truncated bf16 in one dword (lo=a, hi=b)
__device__ __forceinline__ unsigned pk2(float a, float b) {
    unsigned ua = __float_as_uint(a), ub = __float_as_uint(b);
    return (ub & 0xFFFF0000u) | (ua >> 16);
}
__device__ __forceinline__ f32x4 mfma_16x16x32(bf16x8 a, bf16x8 b, f32x4 c) {
    return __builtin_amdgcn_mfma_f32_16x16x32_bf16(a, b, c, 0, 0, 0);
}
// async global->LDS, 16B per lane. LDS dest = wave-uniform base + lane*16.
__device__ __forceinline__ void gld_lds16(const u16* g, u16* l) {
    __builtin_amdgcn_global_load_lds(
        (const __attribute__((address_space(1))) unsigned int*)g,
        (__attribute__((address_space(3))) unsigned int*)l,
        16, 0, 0);
}

#define VSTRIDE 2080
#define LOG2E 1.44269504f

// ---------------------------------------------------------------------------
// prep: inputs f32->bf16 [0,4096); W_in T+cvt [4096,7168); W_out T+cvt [7168,8192)
// ---------------------------------------------------------------------------
__global__ __launch_bounds__(256) void prep(const float* __restrict__ inputs,
                                            u16* __restrict__ inB,
                                            const float* __restrict__ W_in,
                                            u16* __restrict__ WtB,
                                            const float* __restrict__ W_out,
                                            u16* __restrict__ WotB) {
    __shared__ float T[32][33];
    const int bx = blockIdx.x;
    if (bx < 4096) {
        int i = (bx * 256 + threadIdx.x) * 4;
        float4 v = *(const float4*)(inputs + i);
        ushort4 o;
        o.x = f2b(v.x); o.y = f2b(v.y); o.z = f2b(v.z); o.w = f2b(v.w);
        *(ushort4*)(inB + i) = o;
        return;
    }
    const float* src; u16* dst; int R, C, c0, r0;
    if (bx < 7168) {
        int t = bx - 4096; src = W_in; dst = WtB; R = 1024; C = 3072;
        c0 = (t % 96) * 32; r0 = (t / 96) * 32;
    } else {
        int t = bx - 7168; src = W_out; dst = WotB; R = 1024; C = 1024;
        c0 = (t % 32) * 32; r0 = (t / 32) * 32;
    }
    int tr = threadIdx.x >> 5, tc = threadIdx.x & 31;
#pragma unroll
    for (int p = 0; p < 4; ++p)
        T[tr + p * 8][tc] = src[(size_t)(r0 + tr + p * 8) * C + c0 + tc];
    __syncthreads();
#pragma unroll
    for (int p = 0; p < 4; ++p)
        dst[(size_t)(c0 + tr + p * 8) * R + r0 + tc] = f2b(T[tc][tr + p * 8]);
}

// ---------------------------------------------------------------------------
// GEMM (gemm1): C[M,N] = A[M,K] * Bt[N,K]^T. bf16 in, f32 accum.
// v18: SINGLE barrier per K-step: vmcnt(0) -> s_barrier -> stage(next) ->
// compute(cur) -> lgkm(0). Safety: a wave reaches the barrier of step ki only
// after its lgkm(0) of ki-1 (its reads of buf[cur^1] drained), so the
// post-barrier stage into buf[cur^1] is race-free; vmcnt(0) before the
// barrier covers each wave's own cooperative loads, barrier covers all.
// ---------------------------------------------------------------------------
template <int BM, bool F32OUT>
__global__ __launch_bounds__(256) void gemm_tn(const u16* __restrict__ A,
                                               const u16* __restrict__ Bt,
                                               void* __restrict__ Cv,
                                               int M, int N, int K) {
    __shared__ u16 As[2][BM * 32];
    __shared__ u16 Bs[2][128 * 32];
    const int tid = threadIdx.x;
    const int m0 = blockIdx.y * BM;
    const int n0 = blockIdx.x * 128;
    const int w = tid >> 6, lane = tid & 63;
    const int col16 = lane & 15, quad = lane >> 4;
    constexpr int MI = BM / 32;                  // 4 for BM=128
    const int wm = (w >> 1) * (BM / 2), wn = (w & 1) * 64;
    const int srow = (lane >> 2), sseg = (lane & 3) * 8;

    f32x4 acc[MI][4];
#pragma unroll
    for (int i = 0; i < MI; ++i)
#pragma unroll
        for (int j = 0; j < 4; ++j) acc[i][j] = (f32x4){0.f, 0.f, 0.f, 0.f};

    // ---- prologue: stage k-step 0 into buf 0 ----
    if (BM == 128) {
#pragma unroll
        for (int cc = 0; cc < 2; ++cc) {
            int c = w * 2 + cc, row = c * 16 + srow;
            gld_lds16(A + (size_t)(m0 + row) * K + sseg, &As[0][c * 512 + lane * 8]);
            gld_lds16(Bt + (size_t)(n0 + row) * K + sseg, &Bs[0][c * 512 + lane * 8]);
        }
    } else {
        int row = w * 16 + srow;
        gld_lds16(A + (size_t)(m0 + row) * K + sseg, &As[0][w * 512 + lane * 8]);
#pragma unroll
        for (int cc = 0; cc < 2; ++cc) {
            int c = w * 2 + cc, rowb = c * 16 + srow;
            gld_lds16(Bt + (size_t)(n0 + rowb) * K + sseg, &Bs[0][c * 512 + lane * 8]);
        }
    }

    const int NK = K >> 5;
    for (int ki = 0; ki < NK; ++ki) {
        const int cur = ki & 1;
        // my stage(ki) loads landed; all waves' landed + prior reads drained
        asm volatile("s_waitcnt vmcnt(0)" ::: "memory");
        asm volatile("s_barrier" ::: "memory");

        // ---- issue next k-step's stage (hides under this step's compute) ----
        if (ki + 1 < NK) {
            const int kt = (ki + 1) << 5;
            if (BM == 128) {
#pragma unroll
                for (int cc = 0; cc < 2; ++cc) {
                    int c = w * 2 + cc, row = c * 16 + srow;
                    gld_lds16(A + (size_t)(m0 + row) * K + kt + sseg, &As[cur ^ 1][c * 512 + lane * 8]);
                    gld_lds16(Bt + (size_t)(n0 + row) * K + kt + sseg, &Bs[cur ^ 1][c * 512 + lane * 8]);
                }
            } else {
                int row = w * 16 + srow;
                gld_lds16(A + (size_t)(m0 + row) * K + kt + sseg, &As[cur ^ 1][w * 512 + lane * 8]);
#pragma unroll
                for (int cc = 0; cc < 2; ++cc) {
                    int c = w * 2 + cc, rowb = c * 16 + srow;
                    gld_lds16(Bt + (size_t)(n0 + rowb) * K + kt + sseg, &Bs[cur ^ 1][c * 512 + lane * 8]);
                }
            }
        }

        bf16x8 af[MI], bfr[4];
#pragma unroll
        for (int i = 0; i < MI; ++i)
            af[i] = *(const bf16x8*)&As[cur][(wm + i * 16 + col16) * 32 + quad * 8];
#pragma unroll
        for (int j = 0; j < 4; ++j)
            bfr[j] = *(const bf16x8*)&Bs[cur][(wn + j * 16 + col16) * 32 + quad * 8];
#pragma unroll
        for (int i = 0; i < MI; ++i)
#pragma unroll
            for (int j = 0; j < 4; ++j)
                acc[i][j] = mfma_16x16x32(af[i], bfr[j], acc[i][j]);

        // my LDS reads of buf[cur] drained before next step's barrier
        asm volatile("s_waitcnt lgkmcnt(0)" ::: "memory");
    }

#pragma unroll
    for (int i = 0; i < MI; ++i) {
#pragma unroll
        for (int r = 0; r < 4; ++r) {
            int m = m0 + wm + i * 16 + quad * 4 + r;
            if (F32OUT) {
                float* Crow = (float*)Cv + (size_t)m * N + n0 + wn;
#pragma unroll
                for (int j = 0; j < 4; ++j)
                    Crow[j * 16 + col16] = acc[i][j][r];
            } else {
                u16* Crow = (u16*)Cv + (size_t)m * N + n0 + wn;
#pragma unroll
                for (int j = 0; j < 4; ++j)
                    Crow[j * 16 + col16] = f2b(acc[i][j][r]);
            }
        }
    }
}

// ---------------------------------------------------------------------------
// gemm2: C[M,N](f32) = A[M,K] * Bt[N,K]^T, BM=64 x BN=64 x BK=64.
// Grid (N/64, M/64) = 1024 = 4 blocks/CU. XOR-swizzled LDS (both sides).
// v18: same single-barrier K-loop as gemm_tn.
// ---------------------------------------------------------------------------
__global__ __launch_bounds__(256) void gemm_tn64(const u16* __restrict__ A,
                                                 const u16* __restrict__ Bt,
                                                 float* __restrict__ C,
                                                 int M, int N, int K) {
    __shared__ u16 As[2][64 * 64];   // [buf][row][64 k]  (8KB/buf)
    __shared__ u16 Bs[2][64 * 64];
    const int tid = threadIdx.x;
    const int m0 = blockIdx.y * 64;
    const int n0 = blockIdx.x * 64;
    const int w = tid >> 6, lane = tid & 63;
    const int col16 = lane & 15, quad = lane >> 4;
    const int wm = (w >> 1) * 32, wn = (w & 1) * 32;
    // staging decomposition: each gld_lds covers 8 rows x 128B; lane = r*8+s.
    const int sr = lane >> 3;              // row within instr (0..7)
    const int sg = ((lane & 7) ^ sr) * 8;  // pre-swizzled 16B granule (u16 units)
    const int swz = (col16 & 7) << 3;      // row-XOR on fragment reads

    f32x4 acc[2][2];
#pragma unroll
    for (int i = 0; i < 2; ++i)
#pragma unroll
        for (int j = 0; j < 2; ++j) acc[i][j] = (f32x4){0.f, 0.f, 0.f, 0.f};

    // ---- prologue: stage k-step 0 into buf 0 (4 instrs/wave: 2 A + 2 B) ----
#pragma unroll
    for (int i = 0; i < 2; ++i) {
        int c = w * 2 + i;
        gld_lds16(A + (size_t)(m0 + c * 8 + sr) * K + sg, &As[0][c * 512 + lane * 8]);
    }
#pragma unroll
    for (int i = 0; i < 2; ++i) {
        int c = w * 2 + i;
        gld_lds16(Bt + (size_t)(n0 + c * 8 + sr) * K + sg, &Bs[0][c * 512 + lane * 8]);
    }

    const int NK = K >> 6;                 // 16 steps
    for (int ki = 0; ki < NK; ++ki) {
        const int cur = ki & 1;
        asm volatile("s_waitcnt vmcnt(0)" ::: "memory");
        asm volatile("s_barrier" ::: "memory");

        if (ki + 1 < NK) {
            const int kt = (ki + 1) << 6;
#pragma unroll
            for (int i = 0; i < 2; ++i) {
                int c = w * 2 + i;
                gld_lds16(A + (size_t)(m0 + c * 8 + sr) * K + kt + sg, &As[cur ^ 1][c * 512 + lane * 8]);
            }
#pragma unroll
            for (int i = 0; i < 2; ++i) {
                int c = w * 2 + i;
                gld_lds16(Bt + (size_t)(n0 + c * 8 + sr) * K + kt + sg, &Bs[cur ^ 1][c * 512 + lane * 8]);
            }
        }

#pragma unroll
        for (int ks = 0; ks < 2; ++ks) {
            const int ko = (ks * 32 + quad * 8) ^ swz;
            bf16x8 af[2], bfr[2];
#pragma unroll
            for (int i = 0; i < 2; ++i)
                af[i] = *(const bf16x8*)&As[cur][(wm + i * 16 + col16) * 64 + ko];
#pragma unroll
            for (int j = 0; j < 2; ++j)
                bfr[j] = *(const bf16x8*)&Bs[cur][(wn + j * 16 + col16) * 64 + ko];
#pragma unroll
            for (int i = 0; i < 2; ++i)
#pragma unroll
                for (int j = 0; j < 2; ++j)
                    acc[i][j] = mfma_16x16x32(af[i], bfr[j], acc[i][j]);
        }

        asm volatile("s_waitcnt lgkmcnt(0)" ::: "memory");
    }

#pragma unroll
    for (int i = 0; i < 2; ++i) {
#pragma unroll
        for (int r = 0; r < 4; ++r) {
            int m = m0 + wm + i * 16 + quad * 4 + r;
            float* Crow = C + (size_t)m * N + n0 + wn;
#pragma unroll
            for (int j = 0; j < 2; ++j)
                Crow[j * 16 + col16] = acc[i][j][r];
        }
    }
}

// ---------------------------------------------------------------------------
// Fused rope + v_transpose. blocks [0,1024): RoPE (q scaled log2e/8);
// blocks [1024,3072): V transpose into Vt [BH][64][VSTRIDE].
// ---------------------------------------------------------------------------
__global__ __launch_bounds__(256) void rope_vt(const u16* __restrict__ qkv,
                                               const int* __restrict__ segpos,
                                               u16* __restrict__ Qh,
                                               u16* __restrict__ Kh,
                                               u16* __restrict__ Vt) {
    __shared__ u16 T[32][72];
    const int bx = blockIdx.x;
    if (bx < 1024) {
        int t = bx * 256 + threadIdx.x;
        int seg = t & 3;
        int h = (t >> 2) & 15;
        int row = t >> 6;
        float pos = (float)segpos[row];
        const u16* base = qkv + (size_t)row * 3072 + h * 192 + seg * 8;
        union { uint4 u; u16 s[8]; } q1, q2, k1, k2, oq1, oq2, ok1, ok2;
        q1.u = *(const uint4*)(base);
        q2.u = *(const uint4*)(base + 32);
        k1.u = *(const uint4*)(base + 64);
        k2.u = *(const uint4*)(base + 96);
        const float qs = 0.125f * LOG2E;
#pragma unroll
        for (int j = 0; j < 8; ++j) {
            int d = seg * 8 + j;
            float inv_freq = __expf(-(float)d * (9.210340371976184f / 32.0f));
            float ang = pos * inv_freq;
            float c = __cosf(ang), s = __sinf(ang);
            float a1 = b2f(q1.s[j]), a2 = b2f(q2.s[j]);
            float b1 = b2f(k1.s[j]), b2v = b2f(k2.s[j]);
            oq1.s[j] = f2b((a1 * c - a2 * s) * qs);
            oq2.s[j] = f2b((a1 * s + a2 * c) * qs);
            ok1.s[j] = f2b(b1 * c - b2v * s);
            ok2.s[j] = f2b(b1 * s + b2v * c);
        }
        int b = row >> 11, srow = row & 2047;
        size_t idx = ((size_t)(b * 16 + h) * 2048 + srow) * 64 + seg * 8;
        *(uint4*)&Qh[idx]      = oq1.u;
        *(uint4*)&Qh[idx + 32] = oq2.u;
        *(uint4*)&Kh[idx]      = ok1.u;
        *(uint4*)&Kh[idx + 32] = ok2.u;
        return;
    }
    int bxx = bx - 1024;
    int s0 = (bxx & 63) * 32;
    int bh = bxx >> 6;
    int b = bh >> 4, h = bh & 15;
    int t = threadIdx.x;
    {
        int r = t >> 3, seg = t & 7;
        const u16* src = qkv + (size_t)(b * 2048 + s0 + r) * 3072 + h * 192 + 128 + seg * 8;
        *(uint4*)&T[r][seg * 8] = *(const uint4*)src;
    }
    __syncthreads();
    {
        int d = t >> 2, ss = (t & 3) * 8;
        union { uint4 u; u16 s[8]; } w;
#pragma unroll
        for (int j = 0; j < 8; ++j) w.s[j] = T[ss + j][d];
        *(uint4*)(Vt + (size_t)bh * 64 * VSTRIDE + (size_t)d * VSTRIDE + s0 + ss) = w.u;
    }
}

// ---------------------------------------------------------------------------
// Flash attention v18 = v9 compute (P via wave-private LDS -- the verified
// path; v17's shuffle exchange reverted: ds_bpermute doubled bank conflicts)
// with the chunk loop restructured to ONE barrier per chunk:
//   vmcnt(0) -> s_barrier -> stage(ci+1)->buf[cur^1] -> compute(ci) -> lgkm(0)
// Race-freedom: wave reaches barrier of ci only after its lgkm(0) of ci-1
// (reads of buf[cur^1] drained); barrier makes that true for ALL waves, so
// overwriting buf[cur^1] post-barrier is safe. vmcnt(0) pre-barrier covers
// each wave's own cooperative stage; barrier covers everyone's.
// Split-K, tables, swizzle, softmax, epilogue: v9-verbatim.
// ---------------------------------------------------------------------------
#define FIXED_M2 34.6246561f    // 24 * log2(e)

// per-bh unit tables, execution-ordered by descending chunk count (LPT).
__device__ const int UTQ[27] = {6,7,8,9,10,11,12,13,13,14,14,15,15, 5,12, 4,11, 3,10, 2,9, 1,8,15, 0,7,14};
__device__ const int UK0[27] = {0,0,0,0,0,0,0,0,14,0,14,0,14, 0,14, 0,14, 0,14, 0,14, 0,14,28, 0,14,28};
__device__ const int UNC[27] = {14,14,14,14,14,14,14,14,14,14,14,14,14, 12,12, 10,10, 8,8, 6,6, 4,4,4, 2,2,2};
__device__ const int UPS[27] = {-1,0,1,2,3,4,5,6,7,8,9,10,11, -1,12, -1,13, -1,14, -1,15, -1,16,17, -1,18,19};
// reduce tables: tiles tq = 7 + ti, ti in [0,9)
__device__ const int RUN[9]    = {2,2,2,2,2,2,2,3,3};
__device__ const int RUS[9][3] = {{0,18,-1},{1,16,-1},{2,15,-1},{3,14,-1},{4,13,-1},
                                  {5,12,-1},{6,7,-1},{8,9,19},{10,11,17}};

__global__ __launch_bounds__(256) void attn_v18(const u16* __restrict__ Qh,
                                                const u16* __restrict__ Kh,
                                                const u16* __restrict__ Vt,
                                                u16* __restrict__ X,
                                                float* __restrict__ Opart,
                                                float* __restrict__ Lpart) {
    __shared__ u16 Ks[2][64 * 64];   // [buf][k-row][64 d]  (8KB/buf)
    __shared__ u16 Vs[2][64 * 64];   // [buf][d-row][64 k]  (8KB/buf)
    __shared__ u16 Ps[4][32 * 64];   // wave-private P [q][64 k], swizzled
    __shared__ float lred[4][32];
    const int tid = threadIdx.x;
    const int w = tid >> 6, lane = tid & 63;
    const int col16 = lane & 15, quad = lane >> 4;
    // XCD-aware block swizzle: 864 = 8 XCD x 108; each XCD owns 4 bh.
    const int raw = blockIdx.x;
    const int bsw = (raw & 7) * 108 + (raw >> 3);
    const int bh = bsw / 27;
    const int slot = bsw - bh * 27;
    const int tq = UTQ[slot];
    const int c0 = UK0[slot];
    const int nc = UNC[slot];
    const int ps = UPS[slot];
    const int q0 = tq * 128 + w * 32;
    const u16* Qp = Qh + (size_t)bh * 2048 * 64;
    const u16* Kp = Kh + (size_t)bh * 2048 * 64;
    const u16* Vp = Vt + (size_t)bh * 64 * VSTRIDE;
    u16* Pw = Ps[w];
    const int swz = (col16 & 7) << 3;      // row-XOR for all LDS tiles (u16 units)

    // Q fragments (used as B-operand of K*Q^T -- identical lane data)
    bf16x8 qa[2][2];
#pragma unroll
    for (int t = 0; t < 2; ++t)
#pragma unroll
        for (int hf = 0; hf < 2; ++hf)
            qa[t][hf] = *(const bf16x8*)&Qp[(size_t)(q0 + t * 16 + col16) * 64 + hf * 32 + quad * 8];

    float l_acc[2] = {0.f, 0.f};
    f32x4 o[2][4];
#pragma unroll
    for (int t = 0; t < 2; ++t)
#pragma unroll
        for (int f = 0; f < 4; ++f) o[t][f] = (f32x4){0.f, 0.f, 0.f, 0.f};

    // staging decomposition: each gld_lds covers 8 rows x 128B; lane = r*8+s.
    // swizzled granule: global slot = s ^ r  (involution; read applies same XOR)
    const int sr = lane >> 3;              // row within instr (0..7)
    const int sg = ((lane & 7) ^ sr) * 8;  // pre-swizzled 16B granule (u16 units)

    // ---- prologue: stage chunk c0 into buf 0 (4 instrs/wave: 2 K + 2 V) ----
    {
        const int k0 = c0 * 64;
#pragma unroll
        for (int i = 0; i < 2; ++i) {
            int c = w * 2 + i;
            gld_lds16(Kp + (size_t)(k0 + c * 8 + sr) * 64 + sg, &Ks[0][c * 512 + lane * 8]);
        }
#pragma unroll
        for (int i = 0; i < 2; ++i) {
            int c = w * 2 + i;
            gld_lds16(Vp + (size_t)(c * 8 + sr) * VSTRIDE + k0 + sg, &Vs[0][c * 512 + lane * 8]);
        }
    }

    for (int ci = 0; ci < nc; ++ci) {
        const int cur = ci & 1;
        const u16* KsC = Ks[cur];
        const u16* VsC = Vs[cur];

        // my stage(ci) loads landed; barrier: everyone's landed AND everyone's
        // reads of buf[cur^1] (iteration ci-1) are drained
        asm volatile("s_waitcnt vmcnt(0)" ::: "memory");
        asm volatile("s_barrier" ::: "memory");

        // ---- issue next chunk's stage into the other buffer ----
        if (ci + 1 < nc) {
            const int k0n = (c0 + ci + 1) * 64;
            u16* Kd = Ks[cur ^ 1];
            u16* Vd = Vs[cur ^ 1];
#pragma unroll
            for (int i = 0; i < 2; ++i) {
                int c = w * 2 + i;
                gld_lds16(Kp + (size_t)(k0n + c * 8 + sr) * 64 + sg, Kd + c * 512 + lane * 8);
            }
#pragma unroll
            for (int i = 0; i < 2; ++i) {
                int c = w * 2 + i;
                gld_lds16(Vp + (size_t)(c * 8 + sr) * VSTRIDE + k0n + sg, Vd + c * 512 + lane * 8);
            }
        }

        const int k0 = (c0 + ci) * 64;

        // ---- K*Q^T -> S^T ----
        f32x4 s[2][4];
#pragma unroll
        for (int t = 0; t < 2; ++t)
#pragma unroll
            for (int kt = 0; kt < 4; ++kt) s[t][kt] = (f32x4){0.f, 0.f, 0.f, 0.f};
#pragma unroll
        for (int kt = 0; kt < 4; ++kt) {
            const u16* kb = &KsC[(kt * 16 + col16) * 64];
            bf16x8 kf0 = *(const bf16x8*)&kb[(quad * 8) ^ swz];
            bf16x8 kf1 = *(const bf16x8*)&kb[(32 + quad * 8) ^ swz];
            s[0][kt] = mfma_16x16x32(kf0, qa[0][0], s[0][kt]);
            s[0][kt] = mfma_16x16x32(kf1, qa[0][1], s[0][kt]);
            s[1][kt] = mfma_16x16x32(kf0, qa[1][0], s[1][kt]);
            s[1][kt] = mfma_16x16x32(kf1, qa[1][1], s[1][kt]);
        }

        // ---- softmax: p = 2^(s - M2), per-lane l, packed dword P writes ----
        const bool domask = (k0 + 63 > q0);
#pragma unroll
        for (int t = 0; t < 2; ++t) {
            const int qg = q0 + t * 16 + col16;
            float rs = 0.f;
#pragma unroll
            for (int kt = 0; kt < 4; ++kt) {
                float p[4];
#pragma unroll
                for (int r = 0; r < 4; ++r) {
                    float sv = s[t][kt][r];
                    if (domask && (k0 + kt * 16 + quad * 4 + r > qg)) sv = -1e30f;
                    p[r] = __builtin_amdgcn_exp2f(sv - FIXED_M2);
                    rs += p[r];
                }
                unsigned* prow = (unsigned*)&Pw[(t * 16 + col16) * 64 + ((kt * 16 + quad * 4) ^ swz)];
                prow[0] = pk2(p[0], p[1]);
                prow[1] = pk2(p[2], p[3]);
            }
            l_acc[t] += rs;
        }
        asm volatile("s_waitcnt lgkmcnt(0)" ::: "memory");  // P writes -> reads

        // ---- PV: 16 MFMAs ----
#pragma unroll
        for (int ss = 0; ss < 2; ++ss) {
            const int ko = (ss * 32 + quad * 8) ^ swz;
            bf16x8 pf0 = *(const bf16x8*)&Pw[(col16) * 64 + ko];
            bf16x8 pf1 = *(const bf16x8*)&Pw[(16 + col16) * 64 + ko];
#pragma unroll
            for (int f = 0; f < 4; ++f) {
                bf16x8 vf = *(const bf16x8*)&VsC[(f * 16 + col16) * 64 + ko];
                o[0][f] = mfma_16x16x32(pf0, vf, o[0][f]);
                o[1][f] = mfma_16x16x32(pf1, vf, o[1][f]);
            }
        }
        // my LDS reads of buf[cur] drained before next iteration's barrier
        asm volatile("s_waitcnt lgkmcnt(0)" ::: "memory");
    }

    // ---- l reduction across quads (butterfly -> every lane has row total) ----
    float lt[2];
#pragma unroll
    for (int t = 0; t < 2; ++t) {
        float l = l_acc[t];
        l += __shfl_xor(l, 16);
        l += __shfl_xor(l, 32);
        lt[t] = l;
        if (quad == 0) lred[w][t * 16 + col16] = l;
    }
    asm volatile("s_waitcnt lgkmcnt(0)" ::: "memory");

    if (ps >= 0) {
        // ---- partial epilogue: raw O (no divide) + l to workspace ----
        const int pg = bh * 20 + ps;
        float* Op = Opart + ((size_t)pg * 128 + w * 32) * 64;
#pragma unroll
        for (int t = 0; t < 2; ++t) {
#pragma unroll
            for (int r = 0; r < 4; ++r) {
                float* Crow = Op + (t * 16 + quad * 4 + r) * 64;
#pragma unroll
                for (int f = 0; f < 4; ++f)
                    Crow[f * 16 + col16] = o[t][f][r];
            }
        }
        if (quad == 0) {
            float* Lp = Lpart + (size_t)pg * 128 + w * 32;
#pragma unroll
            for (int t = 0; t < 2; ++t) Lp[t * 16 + col16] = lt[t];
        }
        return;
    }

    // ---- direct epilogue (single-unit tile): divide and write X ----
    const int b = bh >> 4, h = bh & 15;
#pragma unroll
    for (int t = 0; t < 2; ++t) {
#pragma unroll
        for (int r = 0; r < 4; ++r) {
            float inv = 1.0f / lred[w][t * 16 + quad * 4 + r];
            int srow = q0 + t * 16 + quad * 4 + r;
            u16* Xp = X + ((size_t)(b * 2048 + srow)) * 1024 + h * 64;
#pragma unroll
            for (int f = 0; f < 4; ++f)
                Xp[f * 16 + col16] = f2b(o[t][f][r] * inv);
        }
    }
}

// ---------------------------------------------------------------------------
// attn_reduce: combine 2-3 partials per (bh, tq in 7..15): X = (sum O)/(sum l)
// ---------------------------------------------------------------------------
__global__ __launch_bounds__(256) void attn_reduce(const float* __restrict__ Opart,
                                                   const float* __restrict__ Lpart,
                                                   u16* __restrict__ X) {
    const int bh = blockIdx.x;           // 0..31
    const int ti = blockIdx.y;           // 0..8 -> tq = 7+ti
    const int tq = 7 + ti;
    const int tid = threadIdx.x;
    const int b = bh >> 4, h = bh & 15;
    const int np = RUN[ti];
    const size_t g0 = (size_t)(bh * 20 + RUS[ti][0]);
    const size_t g1 = (size_t)(bh * 20 + RUS[ti][1]);
    const size_t g2 = (np > 2) ? (size_t)(bh * 20 + RUS[ti][2]) : 0;
    const float4* O0 = (const float4*)Opart + g0 * 2048;
    const float4* O1 = (const float4*)Opart + g1 * 2048;
    const float4* O2 = (const float4*)Opart + g2 * 2048;
#pragma unroll
    for (int i = 0; i < 8; ++i) {
        int e4 = i * 256 + tid;          // float4 index within 128x64 tile
        int q = e4 >> 4, d0 = (e4 & 15) * 4;
        float4 a = O0[e4];
        float4 c = O1[e4];
        a.x += c.x; a.y += c.y; a.z += c.z; a.w += c.w;
        float l = Lpart[g0 * 128 + q] + Lpart[g1 * 128 + q];
        if (np > 2) {
            float4 d = O2[e4];
            a.x += d.x; a.y += d.y; a.z += d.z; a.w += d.w;
            l += Lpart[g2 * 128 + q];
        }
        float inv = 1.0f / l;
        ushort4 ov;
        ov.x = f2b(a.x * inv); ov.y = f2b(a.y * inv);
        ov.z = f2b(a.z * inv); ov.w = f2b(a.w * inv);
        *(ushort4*)&X[((size_t)(b * 2048 + tq * 128 + q)) * 1024 + h * 64 + d0] = ov;
    }
}

// ---------------------------------------------------------------------------
// launch
// ---------------------------------------------------------------------------
extern "C" void kernel_launch(void* const* d_in, const int* in_sizes, int n_in,
                              void* d_out, int out_size, void* d_ws, size_t ws_size,
                              hipStream_t stream) {
    const float* inputs = (const float*)d_in[0];
    const int* segpos   = (const int*)d_in[1];
    const float* W_in   = (const float*)d_in[3];
    const float* W_out  = (const float*)d_in[4];
    float* out = (float*)d_out;

    u16* ws = (u16*)d_ws;
    u16* qkv   = ws;                               // 4096*3072 bf16
    u16* x     = qkv;                              // alias (qkv dead after rope_vt)
    u16* inB   = qkv + 12582912 + 512;
    u16* WtB   = inB + 4194304 + 512;              // W_in^T  [3072][1024]
    u16* WotB  = WtB + 3145728 + 512;              // W_out^T [1024][1024]
    u16* Qh    = WotB + 1048576 + 512;             // [BH][S][64]
    u16* Kh    = Qh + 4194304 + 512;
    u16* Vt    = Kh + 4194304 + 512;               // [BH][64][VSTRIDE]
    // split-K partials live in qkv[8.39M..]/inB/WtB space (dead during attn):
    // Opart: 640 slots x 128 x 64 f32 = 10,485,760 u16; Lpart: 640 x 128 f32.
    float* Opart = (float*)(ws + 8388608);
    float* Lpart = (float*)(ws + 8388608 + 10485760);

    prep<<<dim3(8192), 256, 0, stream>>>(inputs, inB, W_in, WtB, W_out, WotB);
    gemm_tn<128, false><<<dim3(24, 32), 256, 0, stream>>>(inB, WtB, qkv, 4096, 3072, 1024);
    rope_vt<<<dim3(3072), 256, 0, stream>>>(qkv, segpos, Qh, Kh, Vt);
    attn_v18<<<dim3(864), 256, 0, stream>>>(Qh, Kh, Vt, x, Opart, Lpart);
    attn_reduce<<<dim3(32, 9), 256, 0, stream>>>(Opart, Lpart, x);
    gemm_tn64<<<dim3(16, 64), 256, 0, stream>>>(x, WotB, out, 4096, 1024, 1024);
}

// Round 12
// 198.795 us; speedup vs baseline: 1.0393x; 1.0134x over previous
//
#include <hip/hip_runtime.h>

typedef unsigned short u16;
typedef __bf16 bf16x8 __attribute__((ext_vector_type(8)));
typedef float f32x4 __attribute__((ext_vector_type(4)));

__device__ __forceinline__ float b2f(u16 x) {
    union { float f; unsigned u; } v; v.u = ((unsigned)x) << 16; return v.f;
}
__device__ __forceinline__ u16 f2b(float f) {
    union { float f; unsigned u; } v; v.f = f;
    unsigned u = v.u;
    return (u16)((u + 0x7FFFu + ((u >> 16) & 1u)) >> 16);
}
// pack two f32 -> two truncated bf16 in one dword (lo=a, hi=b)
__device__ __forceinline__ unsigned pk2(float a, float b) {
    unsigned ua = __float_as_uint(a), ub = __float_as_uint(b);
    return (ub & 0xFFFF0000u) | (ua >> 16);
}
__device__ __forceinline__ f32x4 mfma_16x16x32(bf16x8 a, bf16x8 b, f32x4 c) {
    return __builtin_amdgcn_mfma_f32_16x16x32_bf16(a, b, c, 0, 0, 0);
}
// async global->LDS, 16B per lane. LDS dest = wave-uniform base + lane*16.
__device__ __forceinline__ void gld_lds16(const u16* g, u16* l) {
    __builtin_amdgcn_global_load_lds(
        (const __attribute__((address_space(1))) unsigned int*)g,
        (__attribute__((address_space(3))) unsigned int*)l,
        16, 0, 0);
}

#define VSTRIDE 2080
#define LOG2E 1.44269504f

// ---------------------------------------------------------------------------
// prep: inputs f32->bf16 [0,4096); W_in T+cvt [4096,7168); W_out T+cvt [7168,8192)
// ---------------------------------------------------------------------------
__global__ __launch_bounds__(256) void prep(const float* __restrict__ inputs,
                                            u16* __restrict__ inB,
                                            const float* __restrict__ W_in,
                                            u16* __restrict__ WtB,
                                            const float* __restrict__ W_out,
                                            u16* __restrict__ WotB) {
    __shared__ float T[32][33];
    const int bx = blockIdx.x;
    if (bx < 4096) {
        int i = (bx * 256 + threadIdx.x) * 4;
        float4 v = *(const float4*)(inputs + i);
        ushort4 o;
        o.x = f2b(v.x); o.y = f2b(v.y); o.z = f2b(v.z); o.w = f2b(v.w);
        *(ushort4*)(inB + i) = o;
        return;
    }
    const float* src; u16* dst; int R, C, c0, r0;
    if (bx < 7168) {
        int t = bx - 4096; src = W_in; dst = WtB; R = 1024; C = 3072;
        c0 = (t % 96) * 32; r0 = (t / 96) * 32;
    } else {
        int t = bx - 7168; src = W_out; dst = WotB; R = 1024; C = 1024;
        c0 = (t % 32) * 32; r0 = (t / 32) * 32;
    }
    int tr = threadIdx.x >> 5, tc = threadIdx.x & 31;
#pragma unroll
    for (int p = 0; p < 4; ++p)
        T[tr + p * 8][tc] = src[(size_t)(r0 + tr + p * 8) * C + c0 + tc];
    __syncthreads();
#pragma unroll
    for (int p = 0; p < 4; ++p)
        dst[(size_t)(c0 + tr + p * 8) * R + r0 + tc] = f2b(T[tc][tr + p * 8]);
}

// ---------------------------------------------------------------------------
// gemm1 (v19): C[M,N](bf16) = A[M,K] * Bt[N,K]^T, BM=BN=128, BK=32, but
// 512 threads / 8 waves: wave (w>>2, w&3) owns a 64x32 output sub-tile
// (acc[4][2], 8 MFMA/step). Grid (24,32)=768 = exactly 3 blocks/CU ->
// 24 waves/CU (was 12): doubles per-SIMD instruction streams to hide the
// per-wave serial chain. Same single-barrier K-loop as v18 (verified).
// Staging: 1 A + 1 B gld_lds per wave (w covers rows w*16 + lane>>2).
// ---------------------------------------------------------------------------
__global__ __launch_bounds__(512) void gemm_tn8(const u16* __restrict__ A,
                                                const u16* __restrict__ Bt,
                                                u16* __restrict__ C,
                                                int M, int N, int K) {
    __shared__ u16 As[2][128 * 32];
    __shared__ u16 Bs[2][128 * 32];
    const int tid = threadIdx.x;
    const int m0 = blockIdx.y * 128;
    const int n0 = blockIdx.x * 128;
    const int w = tid >> 6, lane = tid & 63;
    const int col16 = lane & 15, quad = lane >> 4;
    const int wm = (w >> 2) * 64, wn = (w & 3) * 32;
    const int srow = (lane >> 2), sseg = (lane & 3) * 8;

    f32x4 acc[4][2];
#pragma unroll
    for (int i = 0; i < 4; ++i)
#pragma unroll
        for (int j = 0; j < 2; ++j) acc[i][j] = (f32x4){0.f, 0.f, 0.f, 0.f};

    // ---- prologue: stage k-step 0 into buf 0 (1 A + 1 B instr per wave) ----
    {
        int row = w * 16 + srow;
        gld_lds16(A + (size_t)(m0 + row) * K + sseg, &As[0][w * 512 + lane * 8]);
        gld_lds16(Bt + (size_t)(n0 + row) * K + sseg, &Bs[0][w * 512 + lane * 8]);
    }

    const int NK = K >> 5;
    for (int ki = 0; ki < NK; ++ki) {
        const int cur = ki & 1;
        // my stage(ki) landed; barrier: everyone's landed + prior reads drained
        asm volatile("s_waitcnt vmcnt(0)" ::: "memory");
        asm volatile("s_barrier" ::: "memory");

        // ---- issue next k-step's stage (hides under this step's compute) ----
        if (ki + 1 < NK) {
            const int kt = (ki + 1) << 5;
            int row = w * 16 + srow;
            gld_lds16(A + (size_t)(m0 + row) * K + kt + sseg, &As[cur ^ 1][w * 512 + lane * 8]);
            gld_lds16(Bt + (size_t)(n0 + row) * K + kt + sseg, &Bs[cur ^ 1][w * 512 + lane * 8]);
        }

        bf16x8 af[4], bfr[2];
#pragma unroll
        for (int i = 0; i < 4; ++i)
            af[i] = *(const bf16x8*)&As[cur][(wm + i * 16 + col16) * 32 + quad * 8];
#pragma unroll
        for (int j = 0; j < 2; ++j)
            bfr[j] = *(const bf16x8*)&Bs[cur][(wn + j * 16 + col16) * 32 + quad * 8];
#pragma unroll
        for (int i = 0; i < 4; ++i)
#pragma unroll
            for (int j = 0; j < 2; ++j)
                acc[i][j] = mfma_16x16x32(af[i], bfr[j], acc[i][j]);

        // my LDS reads of buf[cur] drained before next step's barrier
        asm volatile("s_waitcnt lgkmcnt(0)" ::: "memory");
    }

#pragma unroll
    for (int i = 0; i < 4; ++i) {
#pragma unroll
        for (int r = 0; r < 4; ++r) {
            int m = m0 + wm + i * 16 + quad * 4 + r;
            u16* Crow = C + (size_t)m * N + n0 + wn;
#pragma unroll
            for (int j = 0; j < 2; ++j)
                Crow[j * 16 + col16] = f2b(acc[i][j][r]);
        }
    }
}

// ---------------------------------------------------------------------------
// gemm2: C[M,N](f32) = A[M,K] * Bt[N,K]^T, BM=64 x BN=64 x BK=64.
// Grid (N/64, M/64) = 1024 = 4 blocks/CU. XOR-swizzled LDS (both sides).
// Single-barrier K-loop (v18, verified).
// ---------------------------------------------------------------------------
__global__ __launch_bounds__(256) void gemm_tn64(const u16* __restrict__ A,
                                                 const u16* __restrict__ Bt,
                                                 float* __restrict__ C,
                                                 int M, int N, int K) {
    __shared__ u16 As[2][64 * 64];   // [buf][row][64 k]  (8KB/buf)
    __shared__ u16 Bs[2][64 * 64];
    const int tid = threadIdx.x;
    const int m0 = blockIdx.y * 64;
    const int n0 = blockIdx.x * 64;
    const int w = tid >> 6, lane = tid & 63;
    const int col16 = lane & 15, quad = lane >> 4;
    const int wm = (w >> 1) * 32, wn = (w & 1) * 32;
    // staging decomposition: each gld_lds covers 8 rows x 128B; lane = r*8+s.
    const int sr = lane >> 3;              // row within instr (0..7)
    const int sg = ((lane & 7) ^ sr) * 8;  // pre-swizzled 16B granule (u16 units)
    const int swz = (col16 & 7) << 3;      // row-XOR on fragment reads

    f32x4 acc[2][2];
#pragma unroll
    for (int i = 0; i < 2; ++i)
#pragma unroll
        for (int j = 0; j < 2; ++j) acc[i][j] = (f32x4){0.f, 0.f, 0.f, 0.f};

    // ---- prologue: stage k-step 0 into buf 0 (4 instrs/wave: 2 A + 2 B) ----
#pragma unroll
    for (int i = 0; i < 2; ++i) {
        int c = w * 2 + i;
        gld_lds16(A + (size_t)(m0 + c * 8 + sr) * K + sg, &As[0][c * 512 + lane * 8]);
    }
#pragma unroll
    for (int i = 0; i < 2; ++i) {
        int c = w * 2 + i;
        gld_lds16(Bt + (size_t)(n0 + c * 8 + sr) * K + sg, &Bs[0][c * 512 + lane * 8]);
    }

    const int NK = K >> 6;                 // 16 steps
    for (int ki = 0; ki < NK; ++ki) {
        const int cur = ki & 1;
        asm volatile("s_waitcnt vmcnt(0)" ::: "memory");
        asm volatile("s_barrier" ::: "memory");

        if (ki + 1 < NK) {
            const int kt = (ki + 1) << 6;
#pragma unroll
            for (int i = 0; i < 2; ++i) {
                int c = w * 2 + i;
                gld_lds16(A + (size_t)(m0 + c * 8 + sr) * K + kt + sg, &As[cur ^ 1][c * 512 + lane * 8]);
            }
#pragma unroll
            for (int i = 0; i < 2; ++i) {
                int c = w * 2 + i;
                gld_lds16(Bt + (size_t)(n0 + c * 8 + sr) * K + kt + sg, &Bs[cur ^ 1][c * 512 + lane * 8]);
            }
        }

#pragma unroll
        for (int ks = 0; ks < 2; ++ks) {
            const int ko = (ks * 32 + quad * 8) ^ swz;
            bf16x8 af[2], bfr[2];
#pragma unroll
            for (int i = 0; i < 2; ++i)
                af[i] = *(const bf16x8*)&As[cur][(wm + i * 16 + col16) * 64 + ko];
#pragma unroll
            for (int j = 0; j < 2; ++j)
                bfr[j] = *(const bf16x8*)&Bs[cur][(wn + j * 16 + col16) * 64 + ko];
#pragma unroll
            for (int i = 0; i < 2; ++i)
#pragma unroll
                for (int j = 0; j < 2; ++j)
                    acc[i][j] = mfma_16x16x32(af[i], bfr[j], acc[i][j]);
        }

        asm volatile("s_waitcnt lgkmcnt(0)" ::: "memory");
    }

#pragma unroll
    for (int i = 0; i < 2; ++i) {
#pragma unroll
        for (int r = 0; r < 4; ++r) {
            int m = m0 + wm + i * 16 + quad * 4 + r;
            float* Crow = C + (size_t)m * N + n0 + wn;
#pragma unroll
            for (int j = 0; j < 2; ++j)
                Crow[j * 16 + col16] = acc[i][j][r];
        }
    }
}

// ---------------------------------------------------------------------------
// Fused rope + v_transpose. blocks [0,1024): RoPE (q scaled log2e/8);
// blocks [1024,3072): V transpose into Vt [BH][64][VSTRIDE].
// ---------------------------------------------------------------------------
__global__ __launch_bounds__(256) void rope_vt(const u16* __restrict__ qkv,
                                               const int* __restrict__ segpos,
                                               u16* __restrict__ Qh,
                                               u16* __restrict__ Kh,
                                               u16* __restrict__ Vt) {
    __shared__ u16 T[32][72];
    const int bx = blockIdx.x;
    if (bx < 1024) {
        int t = bx * 256 + threadIdx.x;
        int seg = t & 3;
        int h = (t >> 2) & 15;
        int row = t >> 6;
        float pos = (float)segpos[row];
        const u16* base = qkv + (size_t)row * 3072 + h * 192 + seg * 8;
        union { uint4 u; u16 s[8]; } q1, q2, k1, k2, oq1, oq2, ok1, ok2;
        q1.u = *(const uint4*)(base);
        q2.u = *(const uint4*)(base + 32);
        k1.u = *(const uint4*)(base + 64);
        k2.u = *(const uint4*)(base + 96);
        const float qs = 0.125f * LOG2E;
#pragma unroll
        for (int j = 0; j < 8; ++j) {
            int d = seg * 8 + j;
            float inv_freq = __expf(-(float)d * (9.210340371976184f / 32.0f));
            float ang = pos * inv_freq;
            float c = __cosf(ang), s = __sinf(ang);
            float a1 = b2f(q1.s[j]), a2 = b2f(q2.s[j]);
            float b1 = b2f(k1.s[j]), b2v = b2f(k2.s[j]);
            oq1.s[j] = f2b((a1 * c - a2 * s) * qs);
            oq2.s[j] = f2b((a1 * s + a2 * c) * qs);
            ok1.s[j] = f2b(b1 * c - b2v * s);
            ok2.s[j] = f2b(b1 * s + b2v * c);
        }
        int b = row >> 11, srow = row & 2047;
        size_t idx = ((size_t)(b * 16 + h) * 2048 + srow) * 64 + seg * 8;
        *(uint4*)&Qh[idx]      = oq1.u;
        *(uint4*)&Qh[idx + 32] = oq2.u;
        *(uint4*)&Kh[idx]      = ok1.u;
        *(uint4*)&Kh[idx + 32] = ok2.u;
        return;
    }
    int bxx = bx - 1024;
    int s0 = (bxx & 63) * 32;
    int bh = bxx >> 6;
    int b = bh >> 4, h = bh & 15;
    int t = threadIdx.x;
    {
        int r = t >> 3, seg = t & 7;
        const u16* src = qkv + (size_t)(b * 2048 + s0 + r) * 3072 + h * 192 + 128 + seg * 8;
        *(uint4*)&T[r][seg * 8] = *(const uint4*)src;
    }
    __syncthreads();
    {
        int d = t >> 2, ss = (t & 3) * 8;
        union { uint4 u; u16 s[8]; } w;
#pragma unroll
        for (int j = 0; j < 8; ++j) w.s[j] = T[ss + j][d];
        *(uint4*)(Vt + (size_t)bh * 64 * VSTRIDE + (size_t)d * VSTRIDE + s0 + ss) = w.u;
    }
}

// ---------------------------------------------------------------------------
// Flash attention v19 = v18's single-barrier chunk loop, re-partitioned to
// 8 waves x 16 q-rows (512 threads). Same LDS bytes (49664), same grid 864,
// same split-K tables/swizzle/softmax -> 3 blocks/CU but 24 waves/CU (was
// 12): doubles per-SIMD independent instruction streams to fill the ~43%
// idle-issue cycles of the per-wave serial chain (QK->exp2->P->PV).
// Per wave: q0 = tq*128 + w*16; 1 K + 1 V gld_lds per chunk (c = w);
// 8 QK + 8 PV MFMAs; 16 exp2.
// ---------------------------------------------------------------------------
#define FIXED_M2 34.6246561f    // 24 * log2(e)

// per-bh unit tables, execution-ordered by descending chunk count (LPT).
__device__ const int UTQ[27] = {6,7,8,9,10,11,12,13,13,14,14,15,15, 5,12, 4,11, 3,10, 2,9, 1,8,15, 0,7,14};
__device__ const int UK0[27] = {0,0,0,0,0,0,0,0,14,0,14,0,14, 0,14, 0,14, 0,14, 0,14, 0,14,28, 0,14,28};
__device__ const int UNC[27] = {14,14,14,14,14,14,14,14,14,14,14,14,14, 12,12, 10,10, 8,8, 6,6, 4,4,4, 2,2,2};
__device__ const int UPS[27] = {-1,0,1,2,3,4,5,6,7,8,9,10,11, -1,12, -1,13, -1,14, -1,15, -1,16,17, -1,18,19};
// reduce tables: tiles tq = 7 + ti, ti in [0,9)
__device__ const int RUN[9]    = {2,2,2,2,2,2,2,3,3};
__device__ const int RUS[9][3] = {{0,18,-1},{1,16,-1},{2,15,-1},{3,14,-1},{4,13,-1},
                                  {5,12,-1},{6,7,-1},{8,9,19},{10,11,17}};

__global__ __launch_bounds__(512) void attn_v19(const u16* __restrict__ Qh,
                                                const u16* __restrict__ Kh,
                                                const u16* __restrict__ Vt,
                                                u16* __restrict__ X,
                                                float* __restrict__ Opart,
                                                float* __restrict__ Lpart) {
    __shared__ u16 Ks[2][64 * 64];   // [buf][k-row][64 d]  (8KB/buf)
    __shared__ u16 Vs[2][64 * 64];   // [buf][d-row][64 k]  (8KB/buf)
    __shared__ u16 Ps[8][16 * 64];   // wave-private P [16 q][64 k], swizzled
    __shared__ float lred[8][16];
    const int tid = threadIdx.x;
    const int w = tid >> 6, lane = tid & 63;
    const int col16 = lane & 15, quad = lane >> 4;
    // XCD-aware block swizzle: 864 = 8 XCD x 108; each XCD owns 4 bh.
    const int raw = blockIdx.x;
    const int bsw = (raw & 7) * 108 + (raw >> 3);
    const int bh = bsw / 27;
    const int slot = bsw - bh * 27;
    const int tq = UTQ[slot];
    const int c0 = UK0[slot];
    const int nc = UNC[slot];
    const int ps = UPS[slot];
    const int q0 = tq * 128 + w * 16;       // 16 q-rows per wave
    const u16* Qp = Qh + (size_t)bh * 2048 * 64;
    const u16* Kp = Kh + (size_t)bh * 2048 * 64;
    const u16* Vp = Vt + (size_t)bh * 64 * VSTRIDE;
    u16* Pw = Ps[w];
    const int swz = (col16 & 7) << 3;      // row-XOR for all LDS tiles (u16 units)

    // Q fragments (B-operand of K*Q^T)
    bf16x8 qa[2];
#pragma unroll
    for (int hf = 0; hf < 2; ++hf)
        qa[hf] = *(const bf16x8*)&Qp[(size_t)(q0 + col16) * 64 + hf * 32 + quad * 8];

    float l_acc = 0.f;
    f32x4 o[4];
#pragma unroll
    for (int f = 0; f < 4; ++f) o[f] = (f32x4){0.f, 0.f, 0.f, 0.f};

    // staging decomposition: each gld_lds covers 8 rows x 128B; lane = r*8+s.
    // swizzled granule: global slot = s ^ r  (involution; read applies same XOR)
    const int sr = lane >> 3;              // row within instr (0..7)
    const int sg = ((lane & 7) ^ sr) * 8;  // pre-swizzled 16B granule (u16 units)

    // ---- prologue: stage chunk c0 into buf 0 (2 instrs/wave: 1 K + 1 V) ----
    {
        const int k0 = c0 * 64;
        gld_lds16(Kp + (size_t)(k0 + w * 8 + sr) * 64 + sg, &Ks[0][w * 512 + lane * 8]);
        gld_lds16(Vp + (size_t)(w * 8 + sr) * VSTRIDE + k0 + sg, &Vs[0][w * 512 + lane * 8]);
    }

    for (int ci = 0; ci < nc; ++ci) {
        const int cur = ci & 1;
        const u16* KsC = Ks[cur];
        const u16* VsC = Vs[cur];

        // my stage(ci) loads landed; barrier: everyone's landed AND everyone's
        // reads of buf[cur^1] (iteration ci-1) are drained
        asm volatile("s_waitcnt vmcnt(0)" ::: "memory");
        asm volatile("s_barrier" ::: "memory");

        // ---- issue next chunk's stage into the other buffer ----
        if (ci + 1 < nc) {
            const int k0n = (c0 + ci + 1) * 64;
            gld_lds16(Kp + (size_t)(k0n + w * 8 + sr) * 64 + sg, &Ks[cur ^ 1][w * 512 + lane * 8]);
            gld_lds16(Vp + (size_t)(w * 8 + sr) * VSTRIDE + k0n + sg, &Vs[cur ^ 1][w * 512 + lane * 8]);
        }

        const int k0 = (c0 + ci) * 64;

        // ---- K*Q^T -> S^T: s[kt][r] = S^T[k=k0+kt*16+quad*4+r][q=q0+col16]
        f32x4 s[4];
#pragma unroll
        for (int kt = 0; kt < 4; ++kt) s[kt] = (f32x4){0.f, 0.f, 0.f, 0.f};
#pragma unroll
        for (int kt = 0; kt < 4; ++kt) {
            const u16* kb = &KsC[(kt * 16 + col16) * 64];
            bf16x8 kf0 = *(const bf16x8*)&kb[(quad * 8) ^ swz];
            bf16x8 kf1 = *(const bf16x8*)&kb[(32 + quad * 8) ^ swz];
            s[kt] = mfma_16x16x32(kf0, qa[0], s[kt]);
            s[kt] = mfma_16x16x32(kf1, qa[1], s[kt]);
        }

        // ---- softmax: p = 2^(s - M2), per-lane l, packed dword P writes ----
        const bool domask = (k0 + 63 > q0);
        {
            const int qg = q0 + col16;
            float rs = 0.f;
#pragma unroll
            for (int kt = 0; kt < 4; ++kt) {
                float p[4];
#pragma unroll
                for (int r = 0; r < 4; ++r) {
                    float sv = s[kt][r];
                    if (domask && (k0 + kt * 16 + quad * 4 + r > qg)) sv = -1e30f;
                    p[r] = __builtin_amdgcn_exp2f(sv - FIXED_M2);
                    rs += p[r];
                }
                unsigned* prow = (unsigned*)&Pw[col16 * 64 + ((kt * 16 + quad * 4) ^ swz)];
                prow[0] = pk2(p[0], p[1]);
                prow[1] = pk2(p[2], p[3]);
            }
            l_acc += rs;
        }
        asm volatile("s_waitcnt lgkmcnt(0)" ::: "memory");  // P writes -> reads

        // ---- PV: 8 MFMAs ----
#pragma unroll
        for (int ss = 0; ss < 2; ++ss) {
            const int ko = (ss * 32 + quad * 8) ^ swz;
            bf16x8 pf = *(const bf16x8*)&Pw[col16 * 64 + ko];
#pragma unroll
            for (int f = 0; f < 4; ++f) {
                bf16x8 vf = *(const bf16x8*)&VsC[(f * 16 + col16) * 64 + ko];
                o[f] = mfma_16x16x32(pf, vf, o[f]);
            }
        }
        // my LDS reads of buf[cur] drained before next iteration's barrier
        asm volatile("s_waitcnt lgkmcnt(0)" ::: "memory");
    }

    // ---- l reduction across quads (butterfly -> every lane has row total) ----
    float lt;
    {
        float l = l_acc;
        l += __shfl_xor(l, 16);
        l += __shfl_xor(l, 32);
        lt = l;
        if (quad == 0) lred[w][col16] = l;
    }
    asm volatile("s_waitcnt lgkmcnt(0)" ::: "memory");

    if (ps >= 0) {
        // ---- partial epilogue: raw O (no divide) + l to workspace ----
        const int pg = bh * 20 + ps;
        float* Op = Opart + ((size_t)pg * 128 + w * 16) * 64;
#pragma unroll
        for (int r = 0; r < 4; ++r) {
            float* Crow = Op + (quad * 4 + r) * 64;
#pragma unroll
            for (int f = 0; f < 4; ++f)
                Crow[f * 16 + col16] = o[f][r];
        }
        if (quad == 0) {
            float* Lp = Lpart + (size_t)pg * 128 + w * 16;
            Lp[col16] = lt;
        }
        return;
    }

    // ---- direct epilogue (single-unit tile): divide and write X ----
    const int b = bh >> 4, h = bh & 15;
#pragma unroll
    for (int r = 0; r < 4; ++r) {
        float inv = 1.0f / lred[w][quad * 4 + r];
        int srow = q0 + quad * 4 + r;
        u16* Xp = X + ((size_t)(b * 2048 + srow)) * 1024 + h * 64;
#pragma unroll
        for (int f = 0; f < 4; ++f)
            Xp[f * 16 + col16] = f2b(o[f][r] * inv);
    }
}

// ---------------------------------------------------------------------------
// attn_reduce: combine 2-3 partials per (bh, tq in 7..15): X = (sum O)/(sum l)
// ---------------------------------------------------------------------------
__global__ __launch_bounds__(256) void attn_reduce(const float* __restrict__ Opart,
                                                   const float* __restrict__ Lpart,
                                                   u16* __restrict__ X) {
    const int bh = blockIdx.x;           // 0..31
    const int ti = blockIdx.y;           // 0..8 -> tq = 7+ti
    const int tq = 7 + ti;
    const int tid = threadIdx.x;
    const int b = bh >> 4, h = bh & 15;
    const int np = RUN[ti];
    const size_t g0 = (size_t)(bh * 20 + RUS[ti][0]);
    const size_t g1 = (size_t)(bh * 20 + RUS[ti][1]);
    const size_t g2 = (np > 2) ? (size_t)(bh * 20 + RUS[ti][2]) : 0;
    const float4* O0 = (const float4*)Opart + g0 * 2048;
    const float4* O1 = (const float4*)Opart + g1 * 2048;
    const float4* O2 = (const float4*)Opart + g2 * 2048;
#pragma unroll
    for (int i = 0; i < 8; ++i) {
        int e4 = i * 256 + tid;          // float4 index within 128x64 tile
        int q = e4 >> 4, d0 = (e4 & 15) * 4;
        float4 a = O0[e4];
        float4 c = O1[e4];
        a.x += c.x; a.y += c.y; a.z += c.z; a.w += c.w;
        float l = Lpart[g0 * 128 + q] + Lpart[g1 * 128 + q];
        if (np > 2) {
            float4 d = O2[e4];
            a.x += d.x; a.y += d.y; a.z += d.z; a.w += d.w;
            l += Lpart[g2 * 128 + q];
        }
        float inv = 1.0f / l;
        ushort4 ov;
        ov.x = f2b(a.x * inv); ov.y = f2b(a.y * inv);
        ov.z = f2b(a.z * inv); ov.w = f2b(a.w * inv);
        *(ushort4*)&X[((size_t)(b * 2048 + tq * 128 + q)) * 1024 + h * 64 + d0] = ov;
    }
}

// ---------------------------------------------------------------------------
// launch
// ---------------------------------------------------------------------------
extern "C" void kernel_launch(void* const* d_in, const int* in_sizes, int n_in,
                              void* d_out, int out_size, void* d_ws, size_t ws_size,
                              hipStream_t stream) {
    const float* inputs = (const float*)d_in[0];
    const int* segpos   = (const int*)d_in[1];
    const float* W_in   = (const float*)d_in[3];
    const float* W_out  = (const float*)d_in[4];
    float* out = (float*)d_out;

    u16* ws = (u16*)d_ws;
    u16* qkv   = ws;                               // 4096*3072 bf16
    u16* x     = qkv;                              // alias (qkv dead after rope_vt)
    u16* inB   = qkv + 12582912 + 512;
    u16* WtB   = inB + 4194304 + 512;              // W_in^T  [3072][1024]
    u16* WotB  = WtB + 3145728 + 512;              // W_out^T [1024][1024]
    u16* Qh    = WotB + 1048576 + 512;             // [BH][S][64]
    u16* Kh    = Qh + 4194304 + 512;
    u16* Vt    = Kh + 4194304 + 512;               // [BH][64][VSTRIDE]
    // split-K partials live in qkv[8.39M..]/inB/WtB space (dead during attn):
    // Opart: 640 slots x 128 x 64 f32 = 10,485,760 u16; Lpart: 640 x 128 f32.
    float* Opart = (float*)(ws + 8388608);
    float* Lpart = (float*)(ws + 8388608 + 10485760);

    prep<<<dim3(8192), 256, 0, stream>>>(inputs, inB, W_in, WtB, W_out, WotB);
    gemm_tn8<<<dim3(24, 32), 512, 0, stream>>>(inB, WtB, qkv, 4096, 3072, 1024);
    rope_vt<<<dim3(3072), 256, 0, stream>>>(qkv, segpos, Qh, Kh, Vt);
    attn_v19<<<dim3(864), 512, 0, stream>>>(Qh, Kh, Vt, x, Opart, Lpart);
    attn_reduce<<<dim3(32, 9), 256, 0, stream>>>(Opart, Lpart, x);
    gemm_tn64<<<dim3(16, 64), 256, 0, stream>>>(x, WotB, out, 4096, 1024, 1024);
}